// Round 3
// baseline (1722.533 us; speedup 1.0000x reference)
//
#include <hip/hip_runtime.h>

#define DT_F 0.01f
#define EPS_F 1e-5f
#define SPB 4   // samples per block (512 threads = 8 waves = 4 sample-pairs)

__device__ __forceinline__ float rl(float v, int l) {
  return __int_as_float(__builtin_amdgcn_readlane(__float_as_int(v), l));
}
__device__ __forceinline__ float sigm(float x) { return 1.0f / (1.0f + __expf(-x)); }
__device__ __forceinline__ float tanhf_fast(float x) {
  float e = __expf(-2.0f * fabsf(x));
  float t = (1.0f - e) / (1.0f + e);
  return x < 0.0f ? -t : t;
}

// evtab[k*B + sid] = (last obs index in event k's window with sample_ids==sid) + 1, or 0.
__global__ void build_evtab_kernel(const int* __restrict__ sample_ids,
                                   const int* __restrict__ time_ptr,
                                   int* __restrict__ evtab, int B, int ope) {
  int k = blockIdx.x;
  int base = time_ptr[k];
  for (int t = threadIdx.x; t < ope; t += blockDim.x) {
    int obs = base + t;
    int sid = sample_ids[obs];
    atomicMax(&evtab[k * B + sid], obs + 1);   // last occurrence wins
  }
}

// 2 waves per sample. lane i holds row i of each gate. Gate weights in VGPRs,
// h exchanged via LDS broadcast reads. role0: r-gate + u K-low; role1: z-gate + u K-high.
__global__ __launch_bounds__(512, 2) void evolve_kernel(
    const float* __restrict__ time_uniq,
    const float* __restrict__ X,
    const float* __restrict__ covs,
    const float* __restrict__ cov_W1, const float* __restrict__ cov_b1,
    const float* __restrict__ cov_W2, const float* __restrict__ cov_b2,
    const float* __restrict__ gb_Wih, const float* __restrict__ gb_Whh,
    const float* __restrict__ gb_bih, const float* __restrict__ gb_bhh,
    const float* __restrict__ gx_b,
    const float* __restrict__ ghr_W, const float* __restrict__ ghz_W,
    const float* __restrict__ ghh_W,
    const int* __restrict__ evtab,
    float* __restrict__ hpath,
    int B, int NE, int n_steps, int IN, int COV)
{
  __shared__ __align__(16) float sBW[3][64][64];  // Bayes Whh rows, b128-slot XOR swizzled (48KB)
  __shared__ float sWih[8][192];                  // Bayes Wih transposed (6KB)
  __shared__ int   sStep[1024];                   // event e fires at grid step sStep[e] (4KB)
  __shared__ __align__(16) float sH [SPB][64];
  __shared__ __align__(16) float sRH[SPB][64];
  __shared__ float sPU[SPB][64];
  __shared__ float sR [SPB][64];
  __shared__ int   sFire[SPB];

  const int tid = threadIdx.x;

  // ---- stage Bayes weights, swizzled: slot q' = q ^ (i&15) within row i ----
  for (int idx = tid; idx < 3 * 64 * 64; idx += blockDim.x) {
    int r = idx >> 6, j = idx & 63;
    int g = r >> 6, i = r & 63;
    int q = j >> 2;
    sBW[g][i][(((q ^ (i & 15)) << 2) | (j & 3))] = gb_Whh[idx];
  }
  for (int idx = tid; idx < 8 * 192; idx += blockDim.x) {
    int kk = idx / 192, r = idx - kk * 192;
    sWih[kk][r] = (kk < IN) ? gb_Wih[r * IN + kk] : 0.0f;
  }
  for (int e = tid; e < 1024; e += blockDim.x) {
    if (e < NE) {
      float tu = time_uniq[e];
      int k0 = (int)floorf((tu - EPS_F) * 100.0f) - 2;
      if (k0 < 0) k0 = 0;
      while ((float)k0 * DT_F + EPS_F < tu) ++k0;
      sStep[e] = k0;
    }
  }
  __syncthreads();
  if (tid == 0) {  // enforce <=1 event per step, in order
    int prev = -1;
    int ne = NE < 1024 ? NE : 1024;
    for (int e = 0; e < ne; ++e) {
      int s = sStep[e];
      if (s < prev + 1) s = prev + 1;
      sStep[e] = s;
      prev = s;
    }
  }

  const int wid = tid >> 6, lane = tid & 63;
  const int s = wid >> 1, role = wid & 1;
  const int b = blockIdx.x * SPB + s;
  const bool alive = (b < B);

  // ---- h0 = tanh(relu(covs @ W1^T + b1) @ W2^T + b2) (role0 computes) ----
  if (role == 0 && alive) {
    float cacc = cov_b1[lane];
    for (int kk = 0; kk < COV; ++kk)
      cacc = fmaf(covs[b * COV + kk], cov_W1[lane * COV + kk], cacc);
    float cl = fmaxf(cacc, 0.0f);
    float hacc = cov_b2[lane];
#pragma unroll
    for (int j = 0; j < 64; ++j)
      hacc = fmaf(rl(cl, j), cov_W2[lane * 64 + j], hacc);
    sH[s][lane] = tanhf_fast(hacc);
  }

  // ---- per-role ODE weights into registers ----
  float4 WG[16];   // role0: ghr row; role1: ghz row
  float4 WU[8];    // ghh row, K-half (role0: j in [0,32), role1: [32,64))
  {
    const float* gw = role ? ghz_W : ghr_W;
    const float4* p = (const float4*)(gw + lane * 64);
#pragma unroll
    for (int q = 0; q < 16; ++q) WG[q] = p[q];
    const float4* pu = (const float4*)(ghh_W + lane * 64 + role * 32);
#pragma unroll
    for (int q = 0; q < 8; ++q) WU[q] = pu[q];
  }
  const float xg    = gx_b[role * 64 + lane];   // role0: xr, role1: xz
  const float xh    = gx_b[128 + lane];
  const float bhh_g = gb_bhh[role * 64 + lane];
  const float bih_g = gb_bih[role * 64 + lane];
  const float bhh_n = gb_bhh[128 + lane];
  const float bih_n = gb_bih[128 + lane];

  int e_next = 0;
  int v_next = (alive && NE > 0) ? evtab[b] : 0;
  if (role == 0 && lane == 0) sFire[s] = (v_next > 0) ? 1 : 0;
  __syncthreads();
  int s_next = (NE > 0) ? sStep[0] : 0x7fffffff;

  const float4* sHv  = (const float4*)sH[s];
  const float4* sRHv = (const float4*)sRH[s];

#pragma unroll 1
  for (int k = 0; k < n_steps; ++k) {
    if (k == s_next) {                        // block-uniform schedule
      int any = sFire[0] | sFire[1] | sFire[2] | sFire[3];
      if (any) {
        const bool fire = alive && (v_next > 0);
        float h_l = 0.f, gacc = 0.f, pn = 0.f, gi_g = 0.f, gi_n = 0.f, gate_b = 0.f;
        if (fire) {
          h_l = sH[s][lane];
          int obs = v_next - 1;
          const float* xp = X + (long)obs * IN;
          float xv[8];
#pragma unroll
          for (int kk = 0; kk < 8; ++kk) xv[kk] = (kk < IN) ? xp[kk] : 0.0f;
          gi_g = bih_g;
          gacc = bhh_g;
#pragma unroll
          for (int kk = 0; kk < 8; ++kk)
            gi_g = fmaf(sWih[kk][role * 64 + lane], xv[kk], gi_g);
          if (role) {
            gi_n = bih_n;
            pn = bhh_n;
#pragma unroll
            for (int kk = 0; kk < 8; ++kk)
              gi_n = fmaf(sWih[kk][128 + lane], xv[kk], gi_n);
          }
#pragma unroll
          for (int q = 0; q < 16; ++q) {
            float4 hv = sHv[q];
            const float4 w = *(const float4*)&sBW[role][lane][((q ^ (lane & 15)) << 2)];
            gacc = fmaf(w.x, hv.x, gacc);
            gacc = fmaf(w.y, hv.y, gacc);
            gacc = fmaf(w.z, hv.z, gacc);
            gacc = fmaf(w.w, hv.w, gacc);
            if ((q >> 3) == role) {           // n-gate matvec, K-half (compile-time per q)
              const float4 wn = *(const float4*)&sBW[2][lane][((q ^ (lane & 15)) << 2)];
              pn = fmaf(wn.x, hv.x, pn);
              pn = fmaf(wn.y, hv.y, pn);
              pn = fmaf(wn.z, hv.z, pn);
              pn = fmaf(wn.w, hv.w, pn);
            }
          }
          gate_b = sigm(gi_g + gacc);         // role0: r_b ; role1: z_b
          if (role == 0) { sR[s][lane] = gate_b; sPU[s][lane] = pn; }
        }
        __syncthreads();
        if (fire && role == 1) {
          float hn = pn + sPU[s][lane];
          float n  = tanhf_fast(gi_n + sR[s][lane] * hn);
          sH[s][lane] = (1.0f - gate_b) * n + gate_b * h_l;
        }
      }
      __syncthreads();   // separates event LDS use / flag reads from updates below
      ++e_next;
      if (e_next < NE && e_next < 1024) {
        s_next = sStep[e_next];
        v_next = alive ? evtab[(long)e_next * B + b] : 0;
      } else {
        s_next = 0x7fffffff;
        v_next = 0;
      }
      if (role == 0 && lane == 0) sFire[s] = (v_next > 0) ? 1 : 0;
      // next read of sFire/sH is beyond the ODE barriers below
    }

    // ---- record h_rec (post-event, pre-ODE) ----
    float h_l = alive ? sH[s][lane] : 0.0f;
    if (alive && role == 0)
      hpath[((long)k * B + b) * 64 + lane] = h_l;

    // ---- phase A: gate matvec (full K, from registers, h broadcast) ----
    float a = xg;
#pragma unroll
    for (int q = 0; q < 16; ++q) {
      float4 hv = sHv[q];
      a = fmaf(WG[q].x, hv.x, a);
      a = fmaf(WG[q].y, hv.y, a);
      a = fmaf(WG[q].z, hv.z, a);
      a = fmaf(WG[q].w, hv.w, a);
    }
    float gate = sigm(a);                    // role0: r ; role1: z
    if (role == 0) sRH[s][lane] = gate * h_l;
    __syncthreads();

    // ---- phase B: u matvec, K split across roles ----
    float pu = 0.0f;
#pragma unroll
    for (int q = 0; q < 8; ++q) {
      float4 rv = sRHv[role * 8 + q];
      pu = fmaf(WU[q].x, rv.x, pu);
      pu = fmaf(WU[q].y, rv.y, pu);
      pu = fmaf(WU[q].z, rv.z, pu);
      pu = fmaf(WU[q].w, rv.w, pu);
    }
    if (role == 0) sPU[s][lane] = pu;
    __syncthreads();

    // ---- combine + state update (role1) ----
    if (role == 1) {
      float u = tanhf_fast(xh + pu + sPU[s][lane]);
      float hnew = fmaf(DT_F * (1.0f - gate), u - h_l, h_l);
      if (alive) sH[s][lane] = hnew;
    }
    __syncthreads();
  }

  float h_l = alive ? sH[s][lane] : 0.0f;
  if (alive && role == 0)
    hpath[((long)n_steps * B + b) * 64 + lane] = h_l;   // h_last
}

// out[row] = relu(h[row] @ W1^T + b1) @ W2^T + b2, rows = (n_steps+1)*B
__global__ __launch_bounds__(256, 2) void head_kernel(
    const float* __restrict__ hpath, const float* __restrict__ W1,
    const float* __restrict__ b1, const float* __restrict__ W2,
    const float* __restrict__ b2, float* __restrict__ out, long nrows)
{
  __shared__ __align__(16) float sW1[64 * 128];
  __shared__ __align__(16) float sH[64 * 128];
  int tid = threadIdx.x;
  for (int idx = tid; idx < 128 * 64; idx += 256) {
    int oc = idx >> 6, j = idx & 63;
    sW1[j * 128 + oc] = W1[idx];
  }
  long row0 = (long)blockIdx.x * 128;
  for (int idx = tid; idx < 128 * 64; idx += 256) {
    int r = idx >> 6, j = idx & 63;
    long row = row0 + r;
    sH[j * 128 + r] = (row < nrows) ? hpath[row * 64 + j] : 0.0f;
  }
  __syncthreads();

  int tr = tid >> 4, tc = tid & 15;
  int r0 = tr * 8, oc0 = tc * 8;
  float acc[8][8];
#pragma unroll
  for (int s = 0; s < 8; ++s)
#pragma unroll
    for (int u = 0; u < 8; ++u) acc[s][u] = 0.0f;

#pragma unroll 4
  for (int j = 0; j < 64; ++j) {
    float4 ha = *(const float4*)&sH[j * 128 + r0];
    float4 hb = *(const float4*)&sH[j * 128 + r0 + 4];
    float4 wa = *(const float4*)&sW1[j * 128 + oc0];
    float4 wb = *(const float4*)&sW1[j * 128 + oc0 + 4];
    float hv[8] = {ha.x, ha.y, ha.z, ha.w, hb.x, hb.y, hb.z, hb.w};
    float wv[8] = {wa.x, wa.y, wa.z, wa.w, wb.x, wb.y, wb.z, wb.w};
#pragma unroll
    for (int s = 0; s < 8; ++s)
#pragma unroll
      for (int u = 0; u < 8; ++u)
        acc[s][u] = fmaf(hv[s], wv[u], acc[s][u]);
  }

  float p[8][2];
#pragma unroll
  for (int s = 0; s < 8; ++s) { p[s][0] = 0.0f; p[s][1] = 0.0f; }
#pragma unroll
  for (int u = 0; u < 8; ++u) {
    float b1v = b1[oc0 + u];
    float w2a = W2[oc0 + u];
    float w2b = W2[128 + oc0 + u];
#pragma unroll
    for (int s = 0; s < 8; ++s) {
      float o = fmaxf(acc[s][u] + b1v, 0.0f);
      p[s][0] = fmaf(o, w2a, p[s][0]);
      p[s][1] = fmaf(o, w2b, p[s][1]);
    }
  }
#pragma unroll
  for (int off = 1; off < 16; off <<= 1) {
#pragma unroll
    for (int s = 0; s < 8; ++s) {
      p[s][0] += __shfl_xor(p[s][0], off);
      p[s][1] += __shfl_xor(p[s][1], off);
    }
  }
  if (tc == 0) {
    float b20 = b2[0], b21 = b2[1];
#pragma unroll
    for (int s = 0; s < 8; ++s) {
      long row = row0 + r0 + s;
      if (row < nrows) {
        out[row * 2 + 0] = p[s][0] + b20;
        out[row * 2 + 1] = p[s][1] + b21;
      }
    }
  }
}

extern "C" void kernel_launch(void* const* d_in, const int* in_sizes, int n_in,
                              void* d_out, int out_size, void* d_ws, size_t ws_size,
                              hipStream_t stream) {
  const float* time_uniq  = (const float*)d_in[0];
  const int*   time_ptr   = (const int*)d_in[1];
  const float* X          = (const float*)d_in[2];
  const int*   sample_ids = (const int*)d_in[3];
  const float* covs       = (const float*)d_in[4];
  const float* cov_W1     = (const float*)d_in[6];
  const float* cov_b1     = (const float*)d_in[7];
  const float* cov_W2     = (const float*)d_in[8];
  const float* cov_b2     = (const float*)d_in[9];
  const float* gb_Wih     = (const float*)d_in[10];
  const float* gb_Whh     = (const float*)d_in[11];
  const float* gb_bih     = (const float*)d_in[12];
  const float* gb_bhh     = (const float*)d_in[13];
  const float* gx_b       = (const float*)d_in[15];
  const float* ghr_W      = (const float*)d_in[16];
  const float* ghz_W      = (const float*)d_in[17];
  const float* ghh_W      = (const float*)d_in[18];
  const float* out_W1     = (const float*)d_in[19];
  const float* out_b1     = (const float*)d_in[20];
  const float* out_W2     = (const float*)d_in[21];
  const float* out_b2     = (const float*)d_in[22];

  int NE   = in_sizes[0];
  int TOT  = in_sizes[3];
  int IN   = in_sizes[2] / TOT;
  int CH   = in_sizes[7];
  int COV  = in_sizes[6] / CH;
  int B    = in_sizes[4] / COV;
  int OUTD = in_sizes[22];
  int n_steps = out_size / (B * OUTD) - 1;
  int OPE  = TOT / NE;

  char* ws = (char*)d_ws;
  int* evtab = (int*)ws;
  size_t evbytes = (size_t)NE * (size_t)B * sizeof(int);
  size_t off1 = (evbytes + 255) & ~(size_t)255;
  float* hpath = (float*)(ws + off1);

  hipMemsetAsync(evtab, 0, evbytes, stream);
  build_evtab_kernel<<<NE, 256, 0, stream>>>(sample_ids, time_ptr, evtab, B, OPE);
  evolve_kernel<<<(B + SPB - 1) / SPB, 512, 0, stream>>>(
      time_uniq, X, covs, cov_W1, cov_b1, cov_W2, cov_b2,
      gb_Wih, gb_Whh, gb_bih, gb_bhh, gx_b, ghr_W, ghz_W, ghh_W,
      evtab, hpath, B, NE, n_steps, IN, COV);
  long nrows = (long)(n_steps + 1) * B;
  int hb = (int)((nrows + 127) / 128);
  head_kernel<<<hb, 256, 0, stream>>>(hpath, out_W1, out_b1, out_W2, out_b2,
                                      (float*)d_out, nrows);
}

// Round 4
// 888.536 us; speedup vs baseline: 1.9386x; 1.9386x over previous
//
#include <hip/hip_runtime.h>

#define DT_F 0.01f
#define EPS_F 1e-5f

__device__ __forceinline__ float rl(float v, int l) {
  return __int_as_float(__builtin_amdgcn_readlane(__float_as_int(v), l));
}
__device__ __forceinline__ float sigm(float x) { return 1.0f / (1.0f + __expf(-x)); }
__device__ __forceinline__ float tanhf_fast(float x) {
  float e = __expf(-2.0f * fabsf(x));
  float t = (1.0f - e) / (1.0f + e);
  return x < 0.0f ? -t : t;
}

// evtab[k*B + sid] = (last obs index in event k's window with sample_ids==sid) + 1, or 0.
__global__ void build_evtab_kernel(const int* __restrict__ sample_ids,
                                   const int* __restrict__ time_ptr,
                                   int* __restrict__ evtab, int B, int ope) {
  int k = blockIdx.x;
  int base = time_ptr[k];
  for (int t = threadIdx.x; t < ope; t += blockDim.x) {
    int obs = base + t;
    int sid = sample_ids[obs];
    atomicMax(&evtab[k * B + sid], obs + 1);   // last occurrence wins
  }
}

// One wave per sample, 4 samples per 256-thread block, no per-step barriers.
// lane i holds h[i]. ODE weights (r,z,u rows) in registers. h / r*h broadcast
// via wave-private LDS slots (uniform-address ds_read_b128). Bayes Whh in
// block LDS, XOR-swizzled (proven 0-conflict in R3).
__global__ __launch_bounds__(256, 1) void evolve_kernel(
    const float* __restrict__ time_uniq,
    const float* __restrict__ X,
    const float* __restrict__ covs,
    const float* __restrict__ cov_W1, const float* __restrict__ cov_b1,
    const float* __restrict__ cov_W2, const float* __restrict__ cov_b2,
    const float* __restrict__ gb_Wih, const float* __restrict__ gb_Whh,
    const float* __restrict__ gb_bih, const float* __restrict__ gb_bhh,
    const float* __restrict__ gx_b,
    const float* __restrict__ ghr_W, const float* __restrict__ ghz_W,
    const float* __restrict__ ghh_W,
    const int* __restrict__ evtab,
    float* __restrict__ hpath,
    int B, int NE, int n_steps, int IN, int COV)
{
  __shared__ __align__(16) float sBW[3][64][64];  // Bayes Whh, b128-slot XOR swizzled (48KB)
  __shared__ float sWih[8][192];                  // Bayes Wih transposed (6KB)
  __shared__ int   sStep[1024];                   // event e fires at grid step sStep[e] (4KB)
  __shared__ __align__(16) float sH [4][64];      // per-wave h copy
  __shared__ __align__(16) float sRH[4][64];      // per-wave r*h copy

  const int tid = threadIdx.x;

  for (int idx = tid; idx < 3 * 64 * 64; idx += blockDim.x) {
    int r = idx >> 6, j = idx & 63;
    int g = r >> 6, i = r & 63;
    int q = j >> 2;
    sBW[g][i][(((q ^ (i & 15)) << 2) | (j & 3))] = gb_Whh[idx];
  }
  for (int idx = tid; idx < 8 * 192; idx += blockDim.x) {
    int kk = idx / 192, r = idx - kk * 192;
    sWih[kk][r] = (kk < IN) ? gb_Wih[r * IN + kk] : 0.0f;
  }
  for (int e = tid; e < 1024; e += blockDim.x) {
    if (e < NE) {
      float tu = time_uniq[e];
      int k0 = (int)floorf((tu - EPS_F) * 100.0f) - 2;
      if (k0 < 0) k0 = 0;
      while ((float)k0 * DT_F + EPS_F < tu) ++k0;
      sStep[e] = k0;
    }
  }
  __syncthreads();
  if (tid == 0) {  // enforce <=1 event per step, in order
    int prev = -1;
    int ne = NE < 1024 ? NE : 1024;
    for (int e = 0; e < ne; ++e) {
      int s = sStep[e];
      if (s < prev + 1) s = prev + 1;
      sStep[e] = s;
      prev = s;
    }
  }
  __syncthreads();

  const int wid = tid >> 6, lane = tid & 63;
  const int s = wid;
  const int b = blockIdx.x * 4 + wid;
  const bool alive = (b < B);

  // ---- h0 = tanh(relu(covs @ W1^T + b1) @ W2^T + b2) ----
  float h_l = 0.0f;
  if (alive) {
    float cacc = cov_b1[lane];
    for (int kk = 0; kk < COV; ++kk)
      cacc = fmaf(covs[b * COV + kk], cov_W1[lane * COV + kk], cacc);
    float cl = fmaxf(cacc, 0.0f);
    float hacc = cov_b2[lane];
#pragma unroll
    for (int j = 0; j < 64; ++j)
      hacc = fmaf(rl(cl, j), cov_W2[lane * 64 + j], hacc);
    h_l = tanhf_fast(hacc);
  }
  sH[s][lane] = h_l;

  // ---- ODE weights (rows) into registers: 48 float4 = 192 VGPRs ----
  float4 WR[16], WZ[16], WU[16];
  {
    const float4* pr = (const float4*)(ghr_W + lane * 64);
    const float4* pz = (const float4*)(ghz_W + lane * 64);
    const float4* pu = (const float4*)(ghh_W + lane * 64);
#pragma unroll
    for (int q = 0; q < 16; ++q) { WR[q] = pr[q]; WZ[q] = pz[q]; WU[q] = pu[q]; }
  }
  const float xr = gx_b[lane], xz = gx_b[64 + lane], xh = gx_b[128 + lane];
  const float bihr = gb_bih[lane], bihz = gb_bih[64 + lane], bihn = gb_bih[128 + lane];
  const float bhhr = gb_bhh[lane], bhhz = gb_bhh[64 + lane], bhhn = gb_bhh[128 + lane];

  int e_next = 0;
  int s_next = (NE > 0) ? sStep[0] : 0x7fffffff;
  int v_next = (alive && NE > 0) ? evtab[b] : 0;
  float xv[8];
#pragma unroll
  for (int kk = 0; kk < 8; ++kk) xv[kk] = 0.0f;
  if (v_next > 0) {
    const float* xp = X + (long)(v_next - 1) * IN;
#pragma unroll
    for (int kk = 0; kk < 8; ++kk) xv[kk] = (kk < IN) ? xp[kk] : 0.0f;
  }

  const float4* sHv  = (const float4*)sH[s];
  const float4* sRHv = (const float4*)sRH[s];

#pragma unroll 1
  for (int k = 0; k < n_steps; ++k) {
    if (k == s_next) {                        // wave-uniform schedule
      if (v_next > 0) {                       // this sample fires (wave-uniform)
        float gir = bihr, giz = bihz, gin = bihn;
#pragma unroll
        for (int kk = 0; kk < 8; ++kk) {
          gir = fmaf(sWih[kk][lane],       xv[kk], gir);
          giz = fmaf(sWih[kk][64 + lane],  xv[kk], giz);
          gin = fmaf(sWih[kk][128 + lane], xv[kk], gin);
        }
        float gr0 = bhhr, gz0 = bhhz, gn0 = bhhn;
        float gr1 = 0.f, gz1 = 0.f, gn1 = 0.f;
#pragma unroll
        for (int q = 0; q < 16; q += 2) {
          float4 hv0 = sHv[q], hv1 = sHv[q + 1];
          const float4 wr0 = *(const float4*)&sBW[0][lane][((q ^ (lane & 15)) << 2)];
          const float4 wz0 = *(const float4*)&sBW[1][lane][((q ^ (lane & 15)) << 2)];
          const float4 wn0 = *(const float4*)&sBW[2][lane][((q ^ (lane & 15)) << 2)];
          const float4 wr1 = *(const float4*)&sBW[0][lane][(((q + 1) ^ (lane & 15)) << 2)];
          const float4 wz1 = *(const float4*)&sBW[1][lane][(((q + 1) ^ (lane & 15)) << 2)];
          const float4 wn1 = *(const float4*)&sBW[2][lane][(((q + 1) ^ (lane & 15)) << 2)];
          gr0 = fmaf(wr0.x, hv0.x, gr0); gr0 = fmaf(wr0.y, hv0.y, gr0);
          gr0 = fmaf(wr0.z, hv0.z, gr0); gr0 = fmaf(wr0.w, hv0.w, gr0);
          gz0 = fmaf(wz0.x, hv0.x, gz0); gz0 = fmaf(wz0.y, hv0.y, gz0);
          gz0 = fmaf(wz0.z, hv0.z, gz0); gz0 = fmaf(wz0.w, hv0.w, gz0);
          gn0 = fmaf(wn0.x, hv0.x, gn0); gn0 = fmaf(wn0.y, hv0.y, gn0);
          gn0 = fmaf(wn0.z, hv0.z, gn0); gn0 = fmaf(wn0.w, hv0.w, gn0);
          gr1 = fmaf(wr1.x, hv1.x, gr1); gr1 = fmaf(wr1.y, hv1.y, gr1);
          gr1 = fmaf(wr1.z, hv1.z, gr1); gr1 = fmaf(wr1.w, hv1.w, gr1);
          gz1 = fmaf(wz1.x, hv1.x, gz1); gz1 = fmaf(wz1.y, hv1.y, gz1);
          gz1 = fmaf(wz1.z, hv1.z, gz1); gz1 = fmaf(wz1.w, hv1.w, gz1);
          gn1 = fmaf(wn1.x, hv1.x, gn1); gn1 = fmaf(wn1.y, hv1.y, gn1);
          gn1 = fmaf(wn1.z, hv1.z, gn1); gn1 = fmaf(wn1.w, hv1.w, gn1);
        }
        float r = sigm(gir + gr0 + gr1);
        float z = sigm(giz + gz0 + gz1);
        float n = tanhf_fast(gin + r * (gn0 + gn1));
        h_l = (1.0f - z) * n + z * h_l;
        sH[s][lane] = h_l;
      }
      ++e_next;
      if (e_next < NE && e_next < 1024) {
        s_next = sStep[e_next];
        v_next = alive ? evtab[(long)e_next * B + b] : 0;
        if (v_next > 0) {                     // prefetch X row for the future firing
          const float* xp = X + (long)(v_next - 1) * IN;
#pragma unroll
          for (int kk = 0; kk < 8; ++kk) xv[kk] = (kk < IN) ? xp[kk] : 0.0f;
        }
      } else {
        s_next = 0x7fffffff;
        v_next = 0;
      }
    }

    if (alive)
      hpath[((long)k * B + b) * 64 + lane] = h_l;   // h_rec (post-event, pre-ODE)

    // ---- phase A: r,z gates (h broadcast from LDS, weights in registers) ----
    float ar0 = xr, az0 = xz, ar1 = 0.f, az1 = 0.f;
    float ar2 = 0.f, az2 = 0.f, ar3 = 0.f, az3 = 0.f;
#pragma unroll
    for (int q = 0; q < 16; q += 4) {
      float4 hv0 = sHv[q], hv1 = sHv[q + 1], hv2 = sHv[q + 2], hv3 = sHv[q + 3];
      ar0 = fmaf(WR[q].x, hv0.x, ar0);     az0 = fmaf(WZ[q].x, hv0.x, az0);
      ar0 = fmaf(WR[q].y, hv0.y, ar0);     az0 = fmaf(WZ[q].y, hv0.y, az0);
      ar0 = fmaf(WR[q].z, hv0.z, ar0);     az0 = fmaf(WZ[q].z, hv0.z, az0);
      ar0 = fmaf(WR[q].w, hv0.w, ar0);     az0 = fmaf(WZ[q].w, hv0.w, az0);
      ar1 = fmaf(WR[q+1].x, hv1.x, ar1);   az1 = fmaf(WZ[q+1].x, hv1.x, az1);
      ar1 = fmaf(WR[q+1].y, hv1.y, ar1);   az1 = fmaf(WZ[q+1].y, hv1.y, az1);
      ar1 = fmaf(WR[q+1].z, hv1.z, ar1);   az1 = fmaf(WZ[q+1].z, hv1.z, az1);
      ar1 = fmaf(WR[q+1].w, hv1.w, ar1);   az1 = fmaf(WZ[q+1].w, hv1.w, az1);
      ar2 = fmaf(WR[q+2].x, hv2.x, ar2);   az2 = fmaf(WZ[q+2].x, hv2.x, az2);
      ar2 = fmaf(WR[q+2].y, hv2.y, ar2);   az2 = fmaf(WZ[q+2].y, hv2.y, az2);
      ar2 = fmaf(WR[q+2].z, hv2.z, ar2);   az2 = fmaf(WZ[q+2].z, hv2.z, az2);
      ar2 = fmaf(WR[q+2].w, hv2.w, ar2);   az2 = fmaf(WZ[q+2].w, hv2.w, az2);
      ar3 = fmaf(WR[q+3].x, hv3.x, ar3);   az3 = fmaf(WZ[q+3].x, hv3.x, az3);
      ar3 = fmaf(WR[q+3].y, hv3.y, ar3);   az3 = fmaf(WZ[q+3].y, hv3.y, az3);
      ar3 = fmaf(WR[q+3].z, hv3.z, ar3);   az3 = fmaf(WZ[q+3].z, hv3.z, az3);
      ar3 = fmaf(WR[q+3].w, hv3.w, ar3);   az3 = fmaf(WZ[q+3].w, hv3.w, az3);
    }
    float r = sigm((ar0 + ar1) + (ar2 + ar3));
    float z = sigm((az0 + az1) + (az2 + az3));
    sRH[s][lane] = r * h_l;

    // ---- phase B: u matvec (r*h broadcast from LDS) ----
    float au0 = xh, au1 = 0.f, au2 = 0.f, au3 = 0.f;
#pragma unroll
    for (int q = 0; q < 16; q += 4) {
      float4 r0 = sRHv[q], r1 = sRHv[q + 1], r2 = sRHv[q + 2], r3 = sRHv[q + 3];
      au0 = fmaf(WU[q].x, r0.x, au0);   au0 = fmaf(WU[q].y, r0.y, au0);
      au0 = fmaf(WU[q].z, r0.z, au0);   au0 = fmaf(WU[q].w, r0.w, au0);
      au1 = fmaf(WU[q+1].x, r1.x, au1); au1 = fmaf(WU[q+1].y, r1.y, au1);
      au1 = fmaf(WU[q+1].z, r1.z, au1); au1 = fmaf(WU[q+1].w, r1.w, au1);
      au2 = fmaf(WU[q+2].x, r2.x, au2); au2 = fmaf(WU[q+2].y, r2.y, au2);
      au2 = fmaf(WU[q+2].z, r2.z, au2); au2 = fmaf(WU[q+2].w, r2.w, au2);
      au3 = fmaf(WU[q+3].x, r3.x, au3); au3 = fmaf(WU[q+3].y, r3.y, au3);
      au3 = fmaf(WU[q+3].z, r3.z, au3); au3 = fmaf(WU[q+3].w, r3.w, au3);
    }
    float u = tanhf_fast((au0 + au1) + (au2 + au3));
    h_l = fmaf(DT_F * (1.0f - z), u - h_l, h_l);
    sH[s][lane] = h_l;
  }

  if (alive)
    hpath[((long)n_steps * B + b) * 64 + lane] = h_l;   // h_last
}

// out[row] = relu(h[row] @ W1^T + b1) @ W2^T + b2, rows = (n_steps+1)*B
__global__ __launch_bounds__(256, 2) void head_kernel(
    const float* __restrict__ hpath, const float* __restrict__ W1,
    const float* __restrict__ b1, const float* __restrict__ W2,
    const float* __restrict__ b2, float* __restrict__ out, long nrows)
{
  __shared__ __align__(16) float sW1[64 * 128];
  __shared__ __align__(16) float sH[64 * 128];
  int tid = threadIdx.x;
  for (int idx = tid; idx < 128 * 64; idx += 256) {
    int oc = idx >> 6, j = idx & 63;
    sW1[j * 128 + oc] = W1[idx];
  }
  long row0 = (long)blockIdx.x * 128;
  for (int idx = tid; idx < 128 * 64; idx += 256) {
    int r = idx >> 6, j = idx & 63;
    long row = row0 + r;
    sH[j * 128 + r] = (row < nrows) ? hpath[row * 64 + j] : 0.0f;
  }
  __syncthreads();

  int tr = tid >> 4, tc = tid & 15;
  int r0 = tr * 8, oc0 = tc * 8;
  float acc[8][8];
#pragma unroll
  for (int s = 0; s < 8; ++s)
#pragma unroll
    for (int u = 0; u < 8; ++u) acc[s][u] = 0.0f;

#pragma unroll 4
  for (int j = 0; j < 64; ++j) {
    float4 ha = *(const float4*)&sH[j * 128 + r0];
    float4 hb = *(const float4*)&sH[j * 128 + r0 + 4];
    float4 wa = *(const float4*)&sW1[j * 128 + oc0];
    float4 wb = *(const float4*)&sW1[j * 128 + oc0 + 4];
    float hv[8] = {ha.x, ha.y, ha.z, ha.w, hb.x, hb.y, hb.z, hb.w};
    float wv[8] = {wa.x, wa.y, wa.z, wa.w, wb.x, wb.y, wb.z, wb.w};
#pragma unroll
    for (int s = 0; s < 8; ++s)
#pragma unroll
      for (int u = 0; u < 8; ++u)
        acc[s][u] = fmaf(hv[s], wv[u], acc[s][u]);
  }

  float p[8][2];
#pragma unroll
  for (int s = 0; s < 8; ++s) { p[s][0] = 0.0f; p[s][1] = 0.0f; }
#pragma unroll
  for (int u = 0; u < 8; ++u) {
    float b1v = b1[oc0 + u];
    float w2a = W2[oc0 + u];
    float w2b = W2[128 + oc0 + u];
#pragma unroll
    for (int s = 0; s < 8; ++s) {
      float o = fmaxf(acc[s][u] + b1v, 0.0f);
      p[s][0] = fmaf(o, w2a, p[s][0]);
      p[s][1] = fmaf(o, w2b, p[s][1]);
    }
  }
#pragma unroll
  for (int off = 1; off < 16; off <<= 1) {
#pragma unroll
    for (int s = 0; s < 8; ++s) {
      p[s][0] += __shfl_xor(p[s][0], off);
      p[s][1] += __shfl_xor(p[s][1], off);
    }
  }
  if (tc == 0) {
    float b20 = b2[0], b21 = b2[1];
#pragma unroll
    for (int s = 0; s < 8; ++s) {
      long row = row0 + r0 + s;
      if (row < nrows) {
        out[row * 2 + 0] = p[s][0] + b20;
        out[row * 2 + 1] = p[s][1] + b21;
      }
    }
  }
}

extern "C" void kernel_launch(void* const* d_in, const int* in_sizes, int n_in,
                              void* d_out, int out_size, void* d_ws, size_t ws_size,
                              hipStream_t stream) {
  const float* time_uniq  = (const float*)d_in[0];
  const int*   time_ptr   = (const int*)d_in[1];
  const float* X          = (const float*)d_in[2];
  const int*   sample_ids = (const int*)d_in[3];
  const float* covs       = (const float*)d_in[4];
  const float* cov_W1     = (const float*)d_in[6];
  const float* cov_b1     = (const float*)d_in[7];
  const float* cov_W2     = (const float*)d_in[8];
  const float* cov_b2     = (const float*)d_in[9];
  const float* gb_Wih     = (const float*)d_in[10];
  const float* gb_Whh     = (const float*)d_in[11];
  const float* gb_bih     = (const float*)d_in[12];
  const float* gb_bhh     = (const float*)d_in[13];
  const float* gx_b       = (const float*)d_in[15];
  const float* ghr_W      = (const float*)d_in[16];
  const float* ghz_W      = (const float*)d_in[17];
  const float* ghh_W      = (const float*)d_in[18];
  const float* out_W1     = (const float*)d_in[19];
  const float* out_b1     = (const float*)d_in[20];
  const float* out_W2     = (const float*)d_in[21];
  const float* out_b2     = (const float*)d_in[22];

  int NE   = in_sizes[0];
  int TOT  = in_sizes[3];
  int IN   = in_sizes[2] / TOT;
  int CH   = in_sizes[7];
  int COV  = in_sizes[6] / CH;
  int B    = in_sizes[4] / COV;
  int OUTD = in_sizes[22];
  int n_steps = out_size / (B * OUTD) - 1;
  int OPE  = TOT / NE;

  char* ws = (char*)d_ws;
  int* evtab = (int*)ws;
  size_t evbytes = (size_t)NE * (size_t)B * sizeof(int);
  size_t off1 = (evbytes + 255) & ~(size_t)255;
  float* hpath = (float*)(ws + off1);

  hipMemsetAsync(evtab, 0, evbytes, stream);
  build_evtab_kernel<<<NE, 256, 0, stream>>>(sample_ids, time_ptr, evtab, B, OPE);
  evolve_kernel<<<(B + 3) / 4, 256, 0, stream>>>(
      time_uniq, X, covs, cov_W1, cov_b1, cov_W2, cov_b2,
      gb_Wih, gb_Whh, gb_bih, gb_bhh, gx_b, ghr_W, ghz_W, ghh_W,
      evtab, hpath, B, NE, n_steps, IN, COV);
  long nrows = (long)(n_steps + 1) * B;
  int hb = (int)((nrows + 127) / 128);
  head_kernel<<<hb, 256, 0, stream>>>(hpath, out_W1, out_b1, out_W2, out_b2,
                                      (float*)d_out, nrows);
}